// Round 1
// baseline (4395.327 us; speedup 1.0000x reference)
//
#include <hip/hip_runtime.h>
#include <hip/hip_bf16.h>
#include <stdint.h>

// Problem: S=512, N=64, E=256, NH=8, HD=32, LH=512.
// Pipeline: convert -> qkv -> attn -> outproj -> gates GEMM -> persistent LSTM -> final proj.

typedef __attribute__((ext_vector_type(8))) short bf16x8;
typedef __attribute__((ext_vector_type(4))) float f32x4;

__device__ __forceinline__ unsigned short f2bf(float f){
  unsigned u = __float_as_uint(f);
  u += 0x7FFFu + ((u >> 16) & 1u);          // RNE
  return (unsigned short)(u >> 16);
}
__device__ __forceinline__ float b2f(unsigned short h){
  return __uint_as_float(((unsigned)h) << 16);
}
__device__ __forceinline__ ushort4 f4tobf(float4 f){
  ushort4 o; o.x=f2bf(f.x); o.y=f2bf(f.y); o.z=f2bf(f.z); o.w=f2bf(f.w); return o;
}

// ---------------- workspace layout (bytes) ----------------
// flags:    [0x0,      0x1000)   32 flags, 128B stride
// h bufs:   [0x10000,  0x30000)  2 x (64x512 bf16)
// pooled:   [0x30000,  0x50000)  64x512 f32
// w_ih bf16:[0x50000,  0x250000)
// combined: [0x800000, 0x2800000) 32768x512 bf16 (cols 0..255 = x, 256..511 = attn_out)
// gates:    [0x3000000,0xB000000) 32768x2048 bf16   (aliases q/k/v/ctx, which die before k_gates)
// q:0x3000000 k:0x4000000 v:0x5000000 ctx:0x6000000 (each 16MB bf16)
// total required ws: 0xB000000 = 184,549,376 B

// K0: w_ih fp32->bf16, and x fp32 -> combined[:, 0:256] bf16
__global__ __launch_bounds__(256) void k_convert(const float* __restrict__ wih,
                                                 const float* __restrict__ x,
                                                 unsigned short* __restrict__ wih_bf,
                                                 unsigned short* __restrict__ comb){
  size_t i = ((size_t)blockIdx.x * 256 + threadIdx.x) * 4;
  if (i < 1048576){
    float4 f = *(const float4*)(wih + i);
    *(ushort4*)(wih_bf + i) = f4tobf(f);
  } else {
    size_t j = i - 1048576;
    if (j < 8388608){
      float4 f = *(const float4*)(x + j);
      size_t m = j >> 8, c = j & 255;
      *(ushort4*)(comb + m*512 + c) = f4tobf(f);
    }
  }
}

// K1: qkv = x @ in_proj_w.T + b ; scale folded into q; writes q/k [n][h][s][d], v transposed [n][h][d][s]
__global__ __launch_bounds__(256) void k_qkv(const unsigned short* __restrict__ xb,
                                             const float* __restrict__ w,
                                             const float* __restrict__ bias,
                                             unsigned short* __restrict__ q,
                                             unsigned short* __restrict__ kk,
                                             unsigned short* __restrict__ v){
  const int nt = blockIdx.x;    // 0..11
  const int mt = blockIdx.y;    // 0..511  (= s, since M-row = s*64+n)
  __shared__ unsigned short Bs[64][264];
  const int t = threadIdx.x;
  { // stage+convert B tile (in_proj_w rows nt*64..+64, k 0..256)
    int row = t >> 2, c0 = (t & 3) * 64;
    const float* src = w + (size_t)(nt*64 + row)*256 + c0;
    #pragma unroll
    for (int i = 0; i < 64; i += 4){
      float4 f = *(const float4*)(src + i);
      *(ushort4*)&Bs[row][c0 + i] = f4tobf(f);
    }
  }
  __syncthreads();
  const int w4 = t >> 6, l = t & 63, lr = l & 15, lc = l >> 4;
  f32x4 acc[4];
  #pragma unroll
  for (int i = 0; i < 4; ++i) acc[i] = (f32x4){0.f,0.f,0.f,0.f};
  const size_t arow = (size_t)(mt*64 + w4*16 + lr) * 512;  // A from combined (bf16 x)
  #pragma unroll
  for (int kt = 0; kt < 8; ++kt){
    bf16x8 a = *(const bf16x8*)(xb + arow + kt*32 + lc*8);
    #pragma unroll
    for (int n4 = 0; n4 < 4; ++n4){
      bf16x8 b = *(const bf16x8*)&Bs[n4*16 + lr][kt*32 + lc*8];
      acc[n4] = __builtin_amdgcn_mfma_f32_16x16x32_bf16(a, b, acc[n4], 0, 0, 0);
    }
  }
  const int s = mt;
  #pragma unroll
  for (int n4 = 0; n4 < 4; ++n4){
    int ncol = nt*64 + n4*16 + lr;
    float bv = bias[ncol];
    int which = ncol >> 8, rem = ncol & 255, hh = rem >> 5, d = rem & 31;
    #pragma unroll
    for (int reg = 0; reg < 4; ++reg){
      int nb = w4*16 + lc*4 + reg;   // batch
      float val = acc[n4][reg] + bv;
      if (which == 0){
        val *= 0.17677669529663687f;  // 1/sqrt(32)
        q[((size_t)(nb*8 + hh)*512 + s)*32 + d] = f2bf(val);
      } else if (which == 1){
        kk[((size_t)(nb*8 + hh)*512 + s)*32 + d] = f2bf(val);
      } else {
        v[((size_t)(nb*8 + hh)*32 + d)*512 + s] = f2bf(val);
      }
    }
  }
}

// K2: attention for one (n,h); Q-tile=32, full-S bf16 score strip in LDS, exp recomputed into PV A-frags
__global__ __launch_bounds__(256) void k_attn(const unsigned short* __restrict__ q,
                                              const unsigned short* __restrict__ k,
                                              const unsigned short* __restrict__ v,
                                              unsigned short* __restrict__ ctx){
  const int nh = blockIdx.x;
  const int n = nh >> 3, h = nh & 7;
  __shared__ unsigned short sc[32][520];
  __shared__ float red[32][8];
  __shared__ float rowmax[32], rowinv[32];
  const unsigned short* qb = q + (size_t)nh * 512 * 32;
  const unsigned short* kb = k + (size_t)nh * 512 * 32;
  const unsigned short* vb = v + (size_t)nh * 32 * 512;
  const int t = threadIdx.x, w4 = t >> 6, l = t & 63, lr = l & 15, lc = l >> 4;
  const int r = t >> 3, cc = t & 7;
  for (int qt = 0; qt < 16; ++qt){
    const int s0 = qt * 32;
    bf16x8 aq0 = *(const bf16x8*)(qb + (size_t)(s0 + lr)*32 + lc*8);
    bf16x8 aq1 = *(const bf16x8*)(qb + (size_t)(s0 + 16 + lr)*32 + lc*8);
    #pragma unroll
    for (int j = 0; j < 8; ++j){
      int ntl = w4*8 + j;
      bf16x8 bk = *(const bf16x8*)(kb + (size_t)(ntl*16 + lr)*32 + lc*8);
      f32x4 d0 = (f32x4){0.f,0.f,0.f,0.f}, d1 = (f32x4){0.f,0.f,0.f,0.f};
      d0 = __builtin_amdgcn_mfma_f32_16x16x32_bf16(aq0, bk, d0, 0, 0, 0);
      d1 = __builtin_amdgcn_mfma_f32_16x16x32_bf16(aq1, bk, d1, 0, 0, 0);
      #pragma unroll
      for (int reg = 0; reg < 4; ++reg){
        sc[lc*4 + reg][ntl*16 + lr]      = f2bf(d0[reg]);
        sc[16 + lc*4 + reg][ntl*16 + lr] = f2bf(d1[reg]);
      }
    }
    __syncthreads();
    float pm = -1e30f;
    for (int i = 0; i < 64; ++i) pm = fmaxf(pm, b2f(sc[r][cc + 8*i]));
    red[r][cc] = pm;
    __syncthreads();
    float mfull = red[r][0];
    #pragma unroll
    for (int i = 1; i < 8; ++i) mfull = fmaxf(mfull, red[r][i]);
    rowmax[r] = mfull;   // benign same-value race across the 8 threads of a row
    __syncthreads();
    float sum = 0.f;
    for (int i = 0; i < 64; ++i) sum += __expf(b2f(sc[r][cc + 8*i]) - mfull);
    red[r][cc] = sum;
    __syncthreads();
    float ss = 0.f;
    #pragma unroll
    for (int i = 0; i < 8; ++i) ss += red[r][i];
    rowinv[r] = 1.f / ss;
    __syncthreads();
    // PV: each wave one 16x16 tile of the 32x32 O
    const int mt = w4 >> 1, ntd = w4 & 1;
    const int arow = mt*16 + lr;
    const float mrow = rowmax[arow];
    f32x4 o = (f32x4){0.f,0.f,0.f,0.f};
    for (int kt = 0; kt < 16; ++kt){
      bf16x8 sv = *(const bf16x8*)&sc[arow][kt*32 + lc*8];
      bf16x8 ap;
      #pragma unroll
      for (int e = 0; e < 8; ++e){
        float p = __expf(b2f((unsigned short)sv[e]) - mrow);
        ap[e] = (short)f2bf(p);
      }
      bf16x8 bv = *(const bf16x8*)(vb + (size_t)(ntd*16 + lr)*512 + kt*32 + lc*8);
      o = __builtin_amdgcn_mfma_f32_16x16x32_bf16(ap, bv, o, 0, 0, 0);
    }
    #pragma unroll
    for (int reg = 0; reg < 4; ++reg){
      int row = mt*16 + lc*4 + reg;
      int d = ntd*16 + lr;
      float val = o[reg] * rowinv[row];
      ctx[((size_t)(s0 + row)*64 + n)*256 + h*32 + d] = f2bf(val);
    }
    __syncthreads();
  }
}

// K3: attn_out = ctx @ mha_out_w.T + b -> combined[:, 256:512]
__global__ __launch_bounds__(256) void k_outproj(const unsigned short* __restrict__ ctx,
                                                 const float* __restrict__ w,
                                                 const float* __restrict__ bias,
                                                 unsigned short* __restrict__ comb){
  const int nt = blockIdx.x;   // 0..3
  const int mt = blockIdx.y;   // 0..511
  __shared__ unsigned short Bs[64][264];
  const int t = threadIdx.x;
  {
    int row = t >> 2, c0 = (t & 3) * 64;
    const float* src = w + (size_t)(nt*64 + row)*256 + c0;
    #pragma unroll
    for (int i = 0; i < 64; i += 4){
      float4 f = *(const float4*)(src + i);
      *(ushort4*)&Bs[row][c0 + i] = f4tobf(f);
    }
  }
  __syncthreads();
  const int w4 = t >> 6, l = t & 63, lr = l & 15, lc = l >> 4;
  f32x4 acc[4];
  #pragma unroll
  for (int i = 0; i < 4; ++i) acc[i] = (f32x4){0.f,0.f,0.f,0.f};
  const size_t arow = (size_t)(mt*64 + w4*16 + lr) * 256;
  #pragma unroll
  for (int kt = 0; kt < 8; ++kt){
    bf16x8 a = *(const bf16x8*)(ctx + arow + kt*32 + lc*8);
    #pragma unroll
    for (int n4 = 0; n4 < 4; ++n4){
      bf16x8 b = *(const bf16x8*)&Bs[n4*16 + lr][kt*32 + lc*8];
      acc[n4] = __builtin_amdgcn_mfma_f32_16x16x32_bf16(a, b, acc[n4], 0, 0, 0);
    }
  }
  #pragma unroll
  for (int n4 = 0; n4 < 4; ++n4){
    int ncol = nt*64 + n4*16 + lr;
    float bv = bias[ncol];
    #pragma unroll
    for (int reg = 0; reg < 4; ++reg){
      int m = mt*64 + w4*16 + lc*4 + reg;
      comb[(size_t)m*512 + 256 + ncol] = f2bf(acc[n4][reg] + bv);
    }
  }
}

// K4: gates_x = combined @ w_ih.T + (b_ih + b_hh), 128x128 tiles, BK=64
__global__ __launch_bounds__(256) void k_gates(const unsigned short* __restrict__ A,
                                               const unsigned short* __restrict__ B,
                                               const float* __restrict__ bih,
                                               const float* __restrict__ bhh,
                                               unsigned short* __restrict__ gates){
  const int ntile = blockIdx.x;  // 0..15
  const int mtile = blockIdx.y;  // 0..255
  __shared__ unsigned short As[128][72], Bss[128][72];
  const int t = threadIdx.x, w4 = t >> 6, l = t & 63, lr = l & 15, lc = l >> 4;
  const int wm = w4 >> 1, wn = w4 & 1;
  f32x4 acc[4][4];
  #pragma unroll
  for (int i = 0; i < 4; ++i)
    #pragma unroll
    for (int j = 0; j < 4; ++j) acc[i][j] = (f32x4){0.f,0.f,0.f,0.f};
  const int srow = t >> 1, half = t & 1;
  const unsigned short* sa = A + (size_t)(mtile*128 + srow)*512 + half*32;
  const unsigned short* sb = B + (size_t)(ntile*128 + srow)*512 + half*32;
  for (int kkk = 0; kkk < 8; ++kkk){
    #pragma unroll
    for (int i = 0; i < 4; ++i){
      *(uint4*)&As [srow][half*32 + i*8] = *(const uint4*)(sa + kkk*64 + i*8);
      *(uint4*)&Bss[srow][half*32 + i*8] = *(const uint4*)(sb + kkk*64 + i*8);
    }
    __syncthreads();
    #pragma unroll
    for (int kt = 0; kt < 2; ++kt){
      bf16x8 af[4], bfr[4];
      #pragma unroll
      for (int i = 0; i < 4; ++i) af[i]  = *(const bf16x8*)&As [wm*64 + i*16 + lr][kt*32 + lc*8];
      #pragma unroll
      for (int i = 0; i < 4; ++i) bfr[i] = *(const bf16x8*)&Bss[wn*64 + i*16 + lr][kt*32 + lc*8];
      #pragma unroll
      for (int i = 0; i < 4; ++i)
        #pragma unroll
        for (int j = 0; j < 4; ++j)
          acc[i][j] = __builtin_amdgcn_mfma_f32_16x16x32_bf16(af[i], bfr[j], acc[i][j], 0, 0, 0);
    }
    __syncthreads();
  }
  #pragma unroll
  for (int i = 0; i < 4; ++i){
    #pragma unroll
    for (int j = 0; j < 4; ++j){
      int ncol = ntile*128 + wn*64 + j*16 + lr;
      float bsum = bih[ncol] + bhh[ncol];
      #pragma unroll
      for (int reg = 0; reg < 4; ++reg){
        int m = mtile*128 + wm*64 + i*16 + lc*4 + reg;
        gates[(size_t)m*2048 + ncol] = f2bf(acc[i][j][reg] + bsum);
      }
    }
  }
}

// K5: persistent LSTM. 32 co-resident WGs, each owns 16 hidden units; per-step flag barrier at agent scope.
// W slice lives in LDS (XOR-swizzled k-chunks); c and pooled-sum live in VGPRs; h double-buffered in global.
__global__ __launch_bounds__(256, 1) void k_lstm(const float* __restrict__ whh,
                                                 const unsigned short* __restrict__ gates,
                                                 unsigned short* __restrict__ hb0,
                                                 unsigned short* __restrict__ hb1,
                                                 float* __restrict__ pooled,
                                                 int* __restrict__ flags){
  const int wg = blockIdx.x;   // 0..31
  const int j0 = wg * 16;
  __shared__ unsigned short Wl[64][512];   // rows: gate*16+unit ; 64KB exactly
  const int t = threadIdx.x, w4 = t >> 6, l = t & 63, lr = l & 15, lc = l >> 4;
  { // stage w_hh slice fp32->bf16 with chunk swizzle: phys_chunk = logical ^ (row&7)
    const int row = t >> 2;
    const int gate = row >> 4, u = row & 15;
    const float* src = whh + (size_t)(gate*512 + j0 + u) * 512;
    const int cbase = (t & 3) * 16;
    #pragma unroll
    for (int i = 0; i < 16; ++i){
      const int lch = cbase + i;
      float4 f0 = *(const float4*)(src + lch*8);
      float4 f1 = *(const float4*)(src + lch*8 + 4);
      const int pch = lch ^ (row & 7);
      *(ushort4*)&Wl[row][pch*8]     = f4tobf(f0);
      *(ushort4*)&Wl[row][pch*8 + 4] = f4tobf(f1);
    }
  }
  float cst[4]  = {0.f,0.f,0.f,0.f};
  float pool[4] = {0.f,0.f,0.f,0.f};
  const int batch0 = w4*16 + lc*4;
  const int unit = lr;
  unsigned short gx[16], nx[16];
  { // prefetch gates_x for step 0
    #pragma unroll
    for (int reg = 0; reg < 4; ++reg)
      #pragma unroll
      for (int gg = 0; gg < 4; ++gg)
        gx[reg*4 + gg] = gates[(size_t)(batch0 + reg)*2048 + gg*512 + j0 + unit];
  }
  __syncthreads();
  unsigned short* hbufs[2] = {hb0, hb1};
  for (int st = 0; st < 512; ++st){
    if (st > 0){
      if (t < 32){
        while (__hip_atomic_load(&flags[t*32], __ATOMIC_RELAXED, __HIP_MEMORY_SCOPE_AGENT) < st) { }
      }
      if (t < 64) __threadfence();   // acquire: invalidate stale L1/L2 before reading remote h
      __syncthreads();
    }
    const unsigned short* hr = hbufs[st & 1];
    // prefetch next step's gates_x early; MFMA loop hides the latency
    if (st < 511){
      const unsigned short* g0 = gates + (size_t)(st + 1) * 64 * 2048;
      #pragma unroll
      for (int reg = 0; reg < 4; ++reg)
        #pragma unroll
        for (int gg = 0; gg < 4; ++gg)
          nx[reg*4 + gg] = g0[(size_t)(batch0 + reg)*2048 + gg*512 + j0 + unit];
    }
    f32x4 acc[4];
    #pragma unroll
    for (int i = 0; i < 4; ++i) acc[i] = (f32x4){0.f,0.f,0.f,0.f};
    const size_t hrow = (size_t)(w4*16 + lr) * 512;
    #pragma unroll
    for (int kt = 0; kt < 16; ++kt){
      bf16x8 a = *(const bf16x8*)(hr + hrow + kt*32 + lc*8);
      #pragma unroll
      for (int gg = 0; gg < 4; ++gg){
        bf16x8 b = *(const bf16x8*)&Wl[gg*16 + lr][(((kt*4) + lc) ^ (lr & 7)) * 8];
        acc[gg] = __builtin_amdgcn_mfma_f32_16x16x32_bf16(a, b, acc[gg], 0, 0, 0);
      }
    }
    unsigned short* hw = hbufs[(st + 1) & 1];
    #pragma unroll
    for (int reg = 0; reg < 4; ++reg){
      float gi = acc[0][reg] + b2f(gx[reg*4 + 0]);
      float gf = acc[1][reg] + b2f(gx[reg*4 + 1]);
      float gc = acc[2][reg] + b2f(gx[reg*4 + 2]);
      float go = acc[3][reg] + b2f(gx[reg*4 + 3]);
      float i_ = 1.f / (1.f + __expf(-gi));
      float f_ = 1.f / (1.f + __expf(-gf));
      float cg = fminf(fmaxf(gc, -20.f), 20.f);
      float e2 = __expf(2.f * cg);
      float g_ = (e2 - 1.f) / (e2 + 1.f);
      float o_ = 1.f / (1.f + __expf(-go));
      float cn = f_ * cst[reg] + i_ * g_;
      cst[reg] = cn;
      float ct = fminf(fmaxf(cn, -20.f), 20.f);
      float e2c = __expf(2.f * ct);
      float th = (e2c - 1.f) / (e2c + 1.f);
      float hh = o_ * th;
      pool[reg] += hh;
      hw[(size_t)(batch0 + reg)*512 + j0 + unit] = f2bf(hh);
    }
    #pragma unroll
    for (int i = 0; i < 16; ++i) gx[i] = nx[i];
    __syncthreads();  // drains every wave's vmcnt -> all h stores in L2
    if (t == 0){
      __threadfence();  // release: write back L2 so other XCDs see h
      __hip_atomic_store(&flags[wg*32], st + 1, __ATOMIC_RELEASE, __HIP_MEMORY_SCOPE_AGENT);
    }
  }
  #pragma unroll
  for (int reg = 0; reg < 4; ++reg)
    pooled[(size_t)(batch0 + reg)*512 + j0 + unit] = pool[reg] * (1.f / 512.f);
}

// K6: out = log_sigmoid(pooled @ proj_w.T + proj_b)
__global__ __launch_bounds__(256) void k_final(const float* __restrict__ pooled,
                                               const float* __restrict__ w,
                                               const float* __restrict__ bias,
                                               float* __restrict__ out){
  const int n = blockIdx.x;
  __shared__ float pr[512];
  const int t = threadIdx.x;
  pr[t]       = pooled[(size_t)n*512 + t];
  pr[t + 256] = pooled[(size_t)n*512 + t + 256];
  __syncthreads();
  const float* wr = w + (size_t)t * 512;
  float s = bias[t];
  for (int i = 0; i < 512; i += 4){
    float4 f = *(const float4*)(wr + i);
    s += f.x*pr[i] + f.y*pr[i+1] + f.z*pr[i+2] + f.w*pr[i+3];
  }
  float rres = fminf(s, 0.f) - log1pf(__expf(-fabsf(s)));
  out[(size_t)n*256 + t] = rres;
}

extern "C" void kernel_launch(void* const* d_in, const int* in_sizes, int n_in,
                              void* d_out, int out_size, void* d_ws, size_t ws_size,
                              hipStream_t stream){
  const float* x      = (const float*)d_in[0];
  const float* in_w   = (const float*)d_in[1];
  const float* in_b   = (const float*)d_in[2];
  const float* mo_w   = (const float*)d_in[3];
  const float* mo_b   = (const float*)d_in[4];
  const float* w_ih   = (const float*)d_in[5];
  const float* w_hh   = (const float*)d_in[6];
  const float* b_ih   = (const float*)d_in[7];
  const float* b_hh   = (const float*)d_in[8];
  const float* proj_w = (const float*)d_in[9];
  const float* proj_b = (const float*)d_in[10];
  uint8_t* ws = (uint8_t*)d_ws;
  int*            flags  = (int*)(ws + 0x0);
  unsigned short* hb0    = (unsigned short*)(ws + 0x10000);
  unsigned short* hb1    = (unsigned short*)(ws + 0x20000);
  float*          pooled = (float*)(ws + 0x30000);
  unsigned short* wihbf  = (unsigned short*)(ws + 0x50000);
  unsigned short* comb   = (unsigned short*)(ws + 0x800000);
  unsigned short* gates  = (unsigned short*)(ws + 0x3000000);
  unsigned short* qbuf   = (unsigned short*)(ws + 0x3000000);  // aliases gates (dead before k_gates)
  unsigned short* kbuf   = (unsigned short*)(ws + 0x4000000);
  unsigned short* vbuf   = (unsigned short*)(ws + 0x5000000);
  unsigned short* ctx    = (unsigned short*)(ws + 0x6000000);

  hipMemsetAsync(ws, 0, 0x30000, stream);  // flags + both h buffers
  hipLaunchKernelGGL(k_convert, dim3(9216),    dim3(256), 0, stream, w_ih, x, wihbf, comb);
  hipLaunchKernelGGL(k_qkv,     dim3(12, 512), dim3(256), 0, stream, comb, in_w, in_b, qbuf, kbuf, vbuf);
  hipLaunchKernelGGL(k_attn,    dim3(512),     dim3(256), 0, stream, qbuf, kbuf, vbuf, ctx);
  hipLaunchKernelGGL(k_outproj, dim3(4, 512),  dim3(256), 0, stream, ctx, mo_w, mo_b, comb);
  hipLaunchKernelGGL(k_gates,   dim3(16, 256), dim3(256), 0, stream, comb, wihbf, b_ih, b_hh, gates);
  hipLaunchKernelGGL(k_lstm,    dim3(32),      dim3(256), 0, stream, w_hh, gates, hb0, hb1, pooled, flags);
  hipLaunchKernelGGL(k_final,   dim3(64),      dim3(256), 0, stream, pooled, proj_w, proj_b, (float*)d_out);
}

// Round 2
// 3810.523 us; speedup vs baseline: 1.1535x; 1.1535x over previous
//
#include <hip/hip_runtime.h>
#include <hip/hip_bf16.h>
#include <stdint.h>

// Problem: S=512, N=64, E=256, NH=8, HD=32, LH=512.
// Pipeline: convert -> qkv -> attn -> outproj -> gates GEMM -> persistent LSTM -> final proj.
// R2: k_lstm sync redesigned — no threadfence (was invalidating L1/L2 every step);
//     h + flags move via relaxed agent-scope (sc0 sc1, uncached) 8B atomics;
//     gates prefetch stays cached. h stores coalesced via 2KB LDS bounce.

typedef __attribute__((ext_vector_type(8))) short bf16x8;
typedef __attribute__((ext_vector_type(4))) float f32x4;

__device__ __forceinline__ unsigned short f2bf(float f){
  unsigned u = __float_as_uint(f);
  u += 0x7FFFu + ((u >> 16) & 1u);          // RNE
  return (unsigned short)(u >> 16);
}
__device__ __forceinline__ float b2f(unsigned short h){
  return __uint_as_float(((unsigned)h) << 16);
}
__device__ __forceinline__ ushort4 f4tobf(float4 f){
  ushort4 o; o.x=f2bf(f.x); o.y=f2bf(f.y); o.z=f2bf(f.z); o.w=f2bf(f.w); return o;
}

// ---------------- workspace layout (bytes) ----------------
// flags:    [0x0,      0x1000)   32 flags, 128B stride
// h bufs:   [0x10000,  0x30000)  2 x (64x512 bf16)
// pooled:   [0x30000,  0x50000)  64x512 f32
// w_ih bf16:[0x50000,  0x250000)
// combined: [0x800000, 0x2800000) 32768x512 bf16 (cols 0..255 = x, 256..511 = attn_out)
// gates:    [0x3000000,0xB000000) 32768x2048 bf16   (aliases q/k/v/ctx, which die before k_gates)
// q:0x3000000 k:0x4000000 v:0x5000000 ctx:0x6000000 (each 16MB bf16)
// total required ws: 0xB000000 = 184,549,376 B

// K0: w_ih fp32->bf16, and x fp32 -> combined[:, 0:256] bf16
__global__ __launch_bounds__(256) void k_convert(const float* __restrict__ wih,
                                                 const float* __restrict__ x,
                                                 unsigned short* __restrict__ wih_bf,
                                                 unsigned short* __restrict__ comb){
  size_t i = ((size_t)blockIdx.x * 256 + threadIdx.x) * 4;
  if (i < 1048576){
    float4 f = *(const float4*)(wih + i);
    *(ushort4*)(wih_bf + i) = f4tobf(f);
  } else {
    size_t j = i - 1048576;
    if (j < 8388608){
      float4 f = *(const float4*)(x + j);
      size_t m = j >> 8, c = j & 255;
      *(ushort4*)(comb + m*512 + c) = f4tobf(f);
    }
  }
}

// K1: qkv = x @ in_proj_w.T + b ; scale folded into q; writes q/k [n][h][s][d], v transposed [n][h][d][s]
__global__ __launch_bounds__(256) void k_qkv(const unsigned short* __restrict__ xb,
                                             const float* __restrict__ w,
                                             const float* __restrict__ bias,
                                             unsigned short* __restrict__ q,
                                             unsigned short* __restrict__ kk,
                                             unsigned short* __restrict__ v){
  const int nt = blockIdx.x;    // 0..11
  const int mt = blockIdx.y;    // 0..511  (= s, since M-row = s*64+n)
  __shared__ unsigned short Bs[64][264];
  const int t = threadIdx.x;
  { // stage+convert B tile (in_proj_w rows nt*64..+64, k 0..256)
    int row = t >> 2, c0 = (t & 3) * 64;
    const float* src = w + (size_t)(nt*64 + row)*256 + c0;
    #pragma unroll
    for (int i = 0; i < 64; i += 4){
      float4 f = *(const float4*)(src + i);
      *(ushort4*)&Bs[row][c0 + i] = f4tobf(f);
    }
  }
  __syncthreads();
  const int w4 = t >> 6, l = t & 63, lr = l & 15, lc = l >> 4;
  f32x4 acc[4];
  #pragma unroll
  for (int i = 0; i < 4; ++i) acc[i] = (f32x4){0.f,0.f,0.f,0.f};
  const size_t arow = (size_t)(mt*64 + w4*16 + lr) * 512;  // A from combined (bf16 x)
  #pragma unroll
  for (int kt = 0; kt < 8; ++kt){
    bf16x8 a = *(const bf16x8*)(xb + arow + kt*32 + lc*8);
    #pragma unroll
    for (int n4 = 0; n4 < 4; ++n4){
      bf16x8 b = *(const bf16x8*)&Bs[n4*16 + lr][kt*32 + lc*8];
      acc[n4] = __builtin_amdgcn_mfma_f32_16x16x32_bf16(a, b, acc[n4], 0, 0, 0);
    }
  }
  const int s = mt;
  #pragma unroll
  for (int n4 = 0; n4 < 4; ++n4){
    int ncol = nt*64 + n4*16 + lr;
    float bv = bias[ncol];
    int which = ncol >> 8, rem = ncol & 255, hh = rem >> 5, d = rem & 31;
    #pragma unroll
    for (int reg = 0; reg < 4; ++reg){
      int nb = w4*16 + lc*4 + reg;   // batch
      float val = acc[n4][reg] + bv;
      if (which == 0){
        val *= 0.17677669529663687f;  // 1/sqrt(32)
        q[((size_t)(nb*8 + hh)*512 + s)*32 + d] = f2bf(val);
      } else if (which == 1){
        kk[((size_t)(nb*8 + hh)*512 + s)*32 + d] = f2bf(val);
      } else {
        v[((size_t)(nb*8 + hh)*32 + d)*512 + s] = f2bf(val);
      }
    }
  }
}

// K2: attention for one (n,h); Q-tile=32, full-S bf16 score strip in LDS, exp recomputed into PV A-frags
__global__ __launch_bounds__(256) void k_attn(const unsigned short* __restrict__ q,
                                              const unsigned short* __restrict__ k,
                                              const unsigned short* __restrict__ v,
                                              unsigned short* __restrict__ ctx){
  const int nh = blockIdx.x;
  const int n = nh >> 3, h = nh & 7;
  __shared__ unsigned short sc[32][520];
  __shared__ float red[32][8];
  __shared__ float rowmax[32], rowinv[32];
  const unsigned short* qb = q + (size_t)nh * 512 * 32;
  const unsigned short* kb = k + (size_t)nh * 512 * 32;
  const unsigned short* vb = v + (size_t)nh * 32 * 512;
  const int t = threadIdx.x, w4 = t >> 6, l = t & 63, lr = l & 15, lc = l >> 4;
  const int r = t >> 3, cc = t & 7;
  for (int qt = 0; qt < 16; ++qt){
    const int s0 = qt * 32;
    bf16x8 aq0 = *(const bf16x8*)(qb + (size_t)(s0 + lr)*32 + lc*8);
    bf16x8 aq1 = *(const bf16x8*)(qb + (size_t)(s0 + 16 + lr)*32 + lc*8);
    #pragma unroll
    for (int j = 0; j < 8; ++j){
      int ntl = w4*8 + j;
      bf16x8 bk = *(const bf16x8*)(kb + (size_t)(ntl*16 + lr)*32 + lc*8);
      f32x4 d0 = (f32x4){0.f,0.f,0.f,0.f}, d1 = (f32x4){0.f,0.f,0.f,0.f};
      d0 = __builtin_amdgcn_mfma_f32_16x16x32_bf16(aq0, bk, d0, 0, 0, 0);
      d1 = __builtin_amdgcn_mfma_f32_16x16x32_bf16(aq1, bk, d1, 0, 0, 0);
      #pragma unroll
      for (int reg = 0; reg < 4; ++reg){
        sc[lc*4 + reg][ntl*16 + lr]      = f2bf(d0[reg]);
        sc[16 + lc*4 + reg][ntl*16 + lr] = f2bf(d1[reg]);
      }
    }
    __syncthreads();
    float pm = -1e30f;
    for (int i = 0; i < 64; ++i) pm = fmaxf(pm, b2f(sc[r][cc + 8*i]));
    red[r][cc] = pm;
    __syncthreads();
    float mfull = red[r][0];
    #pragma unroll
    for (int i = 1; i < 8; ++i) mfull = fmaxf(mfull, red[r][i]);
    rowmax[r] = mfull;   // benign same-value race across the 8 threads of a row
    __syncthreads();
    float sum = 0.f;
    for (int i = 0; i < 64; ++i) sum += __expf(b2f(sc[r][cc + 8*i]) - mfull);
    red[r][cc] = sum;
    __syncthreads();
    float ss = 0.f;
    #pragma unroll
    for (int i = 0; i < 8; ++i) ss += red[r][i];
    rowinv[r] = 1.f / ss;
    __syncthreads();
    // PV: each wave one 16x16 tile of the 32x32 O
    const int mt = w4 >> 1, ntd = w4 & 1;
    const int arow = mt*16 + lr;
    const float mrow = rowmax[arow];
    f32x4 o = (f32x4){0.f,0.f,0.f,0.f};
    for (int kt = 0; kt < 16; ++kt){
      bf16x8 sv = *(const bf16x8*)&sc[arow][kt*32 + lc*8];
      bf16x8 ap;
      #pragma unroll
      for (int e = 0; e < 8; ++e){
        float p = __expf(b2f((unsigned short)sv[e]) - mrow);
        ap[e] = (short)f2bf(p);
      }
      bf16x8 bv = *(const bf16x8*)(vb + (size_t)(ntd*16 + lr)*512 + kt*32 + lc*8);
      o = __builtin_amdgcn_mfma_f32_16x16x32_bf16(ap, bv, o, 0, 0, 0);
    }
    #pragma unroll
    for (int reg = 0; reg < 4; ++reg){
      int row = mt*16 + lc*4 + reg;
      int d = ntd*16 + lr;
      float val = o[reg] * rowinv[row];
      ctx[((size_t)(s0 + row)*64 + n)*256 + h*32 + d] = f2bf(val);
    }
    __syncthreads();
  }
}

// K3: attn_out = ctx @ mha_out_w.T + b -> combined[:, 256:512]
__global__ __launch_bounds__(256) void k_outproj(const unsigned short* __restrict__ ctx,
                                                 const float* __restrict__ w,
                                                 const float* __restrict__ bias,
                                                 unsigned short* __restrict__ comb){
  const int nt = blockIdx.x;   // 0..3
  const int mt = blockIdx.y;   // 0..511
  __shared__ unsigned short Bs[64][264];
  const int t = threadIdx.x;
  {
    int row = t >> 2, c0 = (t & 3) * 64;
    const float* src = w + (size_t)(nt*64 + row)*256 + c0;
    #pragma unroll
    for (int i = 0; i < 64; i += 4){
      float4 f = *(const float4*)(src + i);
      *(ushort4*)&Bs[row][c0 + i] = f4tobf(f);
    }
  }
  __syncthreads();
  const int w4 = t >> 6, l = t & 63, lr = l & 15, lc = l >> 4;
  f32x4 acc[4];
  #pragma unroll
  for (int i = 0; i < 4; ++i) acc[i] = (f32x4){0.f,0.f,0.f,0.f};
  const size_t arow = (size_t)(mt*64 + w4*16 + lr) * 256;
  #pragma unroll
  for (int kt = 0; kt < 8; ++kt){
    bf16x8 a = *(const bf16x8*)(ctx + arow + kt*32 + lc*8);
    #pragma unroll
    for (int n4 = 0; n4 < 4; ++n4){
      bf16x8 b = *(const bf16x8*)&Bs[n4*16 + lr][kt*32 + lc*8];
      acc[n4] = __builtin_amdgcn_mfma_f32_16x16x32_bf16(a, b, acc[n4], 0, 0, 0);
    }
  }
  #pragma unroll
  for (int n4 = 0; n4 < 4; ++n4){
    int ncol = nt*64 + n4*16 + lr;
    float bv = bias[ncol];
    #pragma unroll
    for (int reg = 0; reg < 4; ++reg){
      int m = mt*64 + w4*16 + lc*4 + reg;
      comb[(size_t)m*512 + 256 + ncol] = f2bf(acc[n4][reg] + bv);
    }
  }
}

// K4: gates_x = combined @ w_ih.T + (b_ih + b_hh), 128x128 tiles, BK=64
__global__ __launch_bounds__(256) void k_gates(const unsigned short* __restrict__ A,
                                               const unsigned short* __restrict__ B,
                                               const float* __restrict__ bih,
                                               const float* __restrict__ bhh,
                                               unsigned short* __restrict__ gates){
  const int ntile = blockIdx.x;  // 0..15
  const int mtile = blockIdx.y;  // 0..255
  __shared__ unsigned short As[128][72], Bss[128][72];
  const int t = threadIdx.x, w4 = t >> 6, l = t & 63, lr = l & 15, lc = l >> 4;
  const int wm = w4 >> 1, wn = w4 & 1;
  f32x4 acc[4][4];
  #pragma unroll
  for (int i = 0; i < 4; ++i)
    #pragma unroll
    for (int j = 0; j < 4; ++j) acc[i][j] = (f32x4){0.f,0.f,0.f,0.f};
  const int srow = t >> 1, half = t & 1;
  const unsigned short* sa = A + (size_t)(mtile*128 + srow)*512 + half*32;
  const unsigned short* sb = B + (size_t)(ntile*128 + srow)*512 + half*32;
  for (int kkk = 0; kkk < 8; ++kkk){
    #pragma unroll
    for (int i = 0; i < 4; ++i){
      *(uint4*)&As [srow][half*32 + i*8] = *(const uint4*)(sa + kkk*64 + i*8);
      *(uint4*)&Bss[srow][half*32 + i*8] = *(const uint4*)(sb + kkk*64 + i*8);
    }
    __syncthreads();
    #pragma unroll
    for (int kt = 0; kt < 2; ++kt){
      bf16x8 af[4], bfr[4];
      #pragma unroll
      for (int i = 0; i < 4; ++i) af[i]  = *(const bf16x8*)&As [wm*64 + i*16 + lr][kt*32 + lc*8];
      #pragma unroll
      for (int i = 0; i < 4; ++i) bfr[i] = *(const bf16x8*)&Bss[wn*64 + i*16 + lr][kt*32 + lc*8];
      #pragma unroll
      for (int i = 0; i < 4; ++i)
        #pragma unroll
        for (int j = 0; j < 4; ++j)
          acc[i][j] = __builtin_amdgcn_mfma_f32_16x16x32_bf16(af[i], bfr[j], acc[i][j], 0, 0, 0);
    }
    __syncthreads();
  }
  #pragma unroll
  for (int i = 0; i < 4; ++i){
    #pragma unroll
    for (int j = 0; j < 4; ++j){
      int ncol = ntile*128 + wn*64 + j*16 + lr;
      float bsum = bih[ncol] + bhh[ncol];
      #pragma unroll
      for (int reg = 0; reg < 4; ++reg){
        int m = mtile*128 + wm*64 + i*16 + lc*4 + reg;
        gates[(size_t)m*2048 + ncol] = f2bf(acc[i][j][reg] + bsum);
      }
    }
  }
}

// K5: persistent LSTM. 32 co-resident WGs, each owns 16 hidden units.
// Cross-WG data (h, flags) moves ONLY via relaxed agent-scope atomics (sc0 sc1 -> uncached,
// straight to coherence point). No threadfence -> caches never invalidated -> gates stay L2-hot.
// Ordering: __syncthreads() drains each wave's vmcnt (stores at coherence point) before the
// relaxed flag store; readers poll flags then load h uncached.
__global__ __launch_bounds__(256, 1) void k_lstm(const float* __restrict__ whh,
                                                 const unsigned short* __restrict__ gates,
                                                 unsigned short* __restrict__ hb0,
                                                 unsigned short* __restrict__ hb1,
                                                 float* __restrict__ pooled,
                                                 int* __restrict__ flags){
  const int wg = blockIdx.x;   // 0..31
  const int j0 = wg * 16;
  __shared__ unsigned short Wl[64][512];   // rows: gate*16+unit ; 64KB
  __shared__ unsigned short hst[64*16];    // 2KB bounce for coalesced h stores
  const int t = threadIdx.x, w4 = t >> 6, l = t & 63, lr = l & 15, lc = l >> 4;
  { // stage w_hh slice fp32->bf16 with chunk swizzle: phys_chunk = logical ^ (row&7)
    const int row = t >> 2;
    const int gate = row >> 4, u = row & 15;
    const float* src = whh + (size_t)(gate*512 + j0 + u) * 512;
    const int cbase = (t & 3) * 16;
    #pragma unroll
    for (int i = 0; i < 16; ++i){
      const int lch = cbase + i;
      float4 f0 = *(const float4*)(src + lch*8);
      float4 f1 = *(const float4*)(src + lch*8 + 4);
      const int pch = lch ^ (row & 7);
      *(ushort4*)&Wl[row][pch*8]     = f4tobf(f0);
      *(ushort4*)&Wl[row][pch*8 + 4] = f4tobf(f1);
    }
  }
  float cst[4]  = {0.f,0.f,0.f,0.f};
  float pool[4] = {0.f,0.f,0.f,0.f};
  const int batch0 = w4*16 + lc*4;
  const int unit = lr;
  unsigned short gx[16], nx[16];
  { // prefetch gates_x for step 0 (plain cached loads; gates region is read-only)
    #pragma unroll
    for (int reg = 0; reg < 4; ++reg)
      #pragma unroll
      for (int gg = 0; gg < 4; ++gg)
        gx[reg*4 + gg] = gates[(size_t)(batch0 + reg)*2048 + gg*512 + j0 + unit];
  }
  __syncthreads();
  unsigned short* hbufs[2] = {hb0, hb1};
  for (int st = 0; st < 512; ++st){
    // issue next-step gates prefetch BEFORE the poll so its latency hides behind the wait
    if (st < 511){
      const unsigned short* g0 = gates + (size_t)(st + 1) * 64 * 2048;
      #pragma unroll
      for (int reg = 0; reg < 4; ++reg)
        #pragma unroll
        for (int gg = 0; gg < 4; ++gg)
          nx[reg*4 + gg] = g0[(size_t)(batch0 + reg)*2048 + gg*512 + j0 + unit];
    }
    if (st > 0){
      if (t < 32){
        while (__hip_atomic_load(&flags[t*32], __ATOMIC_RELAXED, __HIP_MEMORY_SCOPE_AGENT) < st) { }
      }
      __syncthreads();
    }
    const unsigned short* hr = hbufs[st & 1];
    f32x4 acc[4];
    #pragma unroll
    for (int i = 0; i < 4; ++i) acc[i] = (f32x4){0.f,0.f,0.f,0.f};
    const size_t hrow = (size_t)(w4*16 + lr) * 512;
    #pragma unroll
    for (int kt = 0; kt < 16; ++kt){
      union { unsigned long long q[2]; bf16x8 v; } ua;
      const unsigned long long* ap = (const unsigned long long*)(hr + hrow + kt*32 + lc*8);
      ua.q[0] = __hip_atomic_load(ap,     __ATOMIC_RELAXED, __HIP_MEMORY_SCOPE_AGENT);
      ua.q[1] = __hip_atomic_load(ap + 1, __ATOMIC_RELAXED, __HIP_MEMORY_SCOPE_AGENT);
      bf16x8 a = ua.v;
      #pragma unroll
      for (int gg = 0; gg < 4; ++gg){
        bf16x8 b = *(const bf16x8*)&Wl[gg*16 + lr][(((kt*4) + lc) ^ (lr & 7)) * 8];
        acc[gg] = __builtin_amdgcn_mfma_f32_16x16x32_bf16(a, b, acc[gg], 0, 0, 0);
      }
    }
    #pragma unroll
    for (int reg = 0; reg < 4; ++reg){
      float gi = acc[0][reg] + b2f(gx[reg*4 + 0]);
      float gf = acc[1][reg] + b2f(gx[reg*4 + 1]);
      float gc = acc[2][reg] + b2f(gx[reg*4 + 2]);
      float go = acc[3][reg] + b2f(gx[reg*4 + 3]);
      float i_ = 1.f / (1.f + __expf(-gi));
      float f_ = 1.f / (1.f + __expf(-gf));
      float cg = fminf(fmaxf(gc, -20.f), 20.f);
      float e2 = __expf(2.f * cg);
      float g_ = (e2 - 1.f) / (e2 + 1.f);
      float o_ = 1.f / (1.f + __expf(-go));
      float cn = f_ * cst[reg] + i_ * g_;
      cst[reg] = cn;
      float ct = fminf(fmaxf(cn, -20.f), 20.f);
      float e2c = __expf(2.f * ct);
      float th = (e2c - 1.f) / (e2c + 1.f);
      float hh = o_ * th;
      pool[reg] += hh;
      hst[(batch0 + reg)*16 + unit] = f2bf(hh);
    }
    #pragma unroll
    for (int i = 0; i < 16; ++i) gx[i] = nx[i];
    __syncthreads();   // hst complete
    { // coalesced uncached h store: 256 threads x 8B = 2KB slice
      unsigned short* hw = hbufs[(st + 1) & 1];
      const int b = t >> 2, o4 = (t & 3) * 4;
      unsigned long long val = *(const unsigned long long*)&hst[b*16 + o4];
      __hip_atomic_store((unsigned long long*)(hw + (size_t)b*512 + j0 + o4), val,
                         __ATOMIC_RELAXED, __HIP_MEMORY_SCOPE_AGENT);
    }
    __syncthreads();   // each wave drains vmcnt before barrier -> all h stores at coherence point
    if (t == 0){
      __hip_atomic_store(&flags[wg*32], st + 1, __ATOMIC_RELAXED, __HIP_MEMORY_SCOPE_AGENT);
    }
  }
  #pragma unroll
  for (int reg = 0; reg < 4; ++reg)
    pooled[(size_t)(batch0 + reg)*512 + j0 + unit] = pool[reg] * (1.f / 512.f);
}

// K6: out = log_sigmoid(pooled @ proj_w.T + proj_b)
__global__ __launch_bounds__(256) void k_final(const float* __restrict__ pooled,
                                               const float* __restrict__ w,
                                               const float* __restrict__ bias,
                                               float* __restrict__ out){
  const int n = blockIdx.x;
  __shared__ float pr[512];
  const int t = threadIdx.x;
  pr[t]       = pooled[(size_t)n*512 + t];
  pr[t + 256] = pooled[(size_t)n*512 + t + 256];
  __syncthreads();
  const float* wr = w + (size_t)t * 512;
  float s = bias[t];
  for (int i = 0; i < 512; i += 4){
    float4 f = *(const float4*)(wr + i);
    s += f.x*pr[i] + f.y*pr[i+1] + f.z*pr[i+2] + f.w*pr[i+3];
  }
  float rres = fminf(s, 0.f) - log1pf(__expf(-fabsf(s)));
  out[(size_t)n*256 + t] = rres;
}

extern "C" void kernel_launch(void* const* d_in, const int* in_sizes, int n_in,
                              void* d_out, int out_size, void* d_ws, size_t ws_size,
                              hipStream_t stream){
  const float* x      = (const float*)d_in[0];
  const float* in_w   = (const float*)d_in[1];
  const float* in_b   = (const float*)d_in[2];
  const float* mo_w   = (const float*)d_in[3];
  const float* mo_b   = (const float*)d_in[4];
  const float* w_ih   = (const float*)d_in[5];
  const float* w_hh   = (const float*)d_in[6];
  const float* b_ih   = (const float*)d_in[7];
  const float* b_hh   = (const float*)d_in[8];
  const float* proj_w = (const float*)d_in[9];
  const float* proj_b = (const float*)d_in[10];
  uint8_t* ws = (uint8_t*)d_ws;
  int*            flags  = (int*)(ws + 0x0);
  unsigned short* hb0    = (unsigned short*)(ws + 0x10000);
  unsigned short* hb1    = (unsigned short*)(ws + 0x20000);
  float*          pooled = (float*)(ws + 0x30000);
  unsigned short* wihbf  = (unsigned short*)(ws + 0x50000);
  unsigned short* comb   = (unsigned short*)(ws + 0x800000);
  unsigned short* gates  = (unsigned short*)(ws + 0x3000000);
  unsigned short* qbuf   = (unsigned short*)(ws + 0x3000000);  // aliases gates (dead before k_gates)
  unsigned short* kbuf   = (unsigned short*)(ws + 0x4000000);
  unsigned short* vbuf   = (unsigned short*)(ws + 0x5000000);
  unsigned short* ctx    = (unsigned short*)(ws + 0x6000000);

  hipMemsetAsync(ws, 0, 0x30000, stream);  // flags + both h buffers
  hipLaunchKernelGGL(k_convert, dim3(9216),    dim3(256), 0, stream, w_ih, x, wihbf, comb);
  hipLaunchKernelGGL(k_qkv,     dim3(12, 512), dim3(256), 0, stream, comb, in_w, in_b, qbuf, kbuf, vbuf);
  hipLaunchKernelGGL(k_attn,    dim3(512),     dim3(256), 0, stream, qbuf, kbuf, vbuf, ctx);
  hipLaunchKernelGGL(k_outproj, dim3(4, 512),  dim3(256), 0, stream, ctx, mo_w, mo_b, comb);
  hipLaunchKernelGGL(k_gates,   dim3(16, 256), dim3(256), 0, stream, comb, wihbf, b_ih, b_hh, gates);
  hipLaunchKernelGGL(k_lstm,    dim3(32),      dim3(256), 0, stream, w_hh, gates, hb0, hb1, pooled, flags);
  hipLaunchKernelGGL(k_final,   dim3(64),      dim3(256), 0, stream, pooled, proj_w, proj_b, (float*)d_out);
}

// Round 3
// 2972.076 us; speedup vs baseline: 1.4789x; 1.2821x over previous
//
#include <hip/hip_runtime.h>
#include <hip/hip_bf16.h>
#include <stdint.h>

// Problem: S=512, N=64, E=256, NH=8, HD=32, LH=512.
// Pipeline: convert -> qkv -> attn -> outproj -> gates GEMM -> persistent LSTM -> final proj.
// R3: k_lstm data-path rework:
//  - gates retiled by k_gates to [st][wg][batch][unit][gate] -> 8KB contiguous per (st,wg),
//    prefetch = 4x8B coalesced cached loads (was 16x2B scatter, 3x HBM overfetch).
//  - h double-buffer -> 512-slot ring (overlaid on dead `combined` buffer). Each h address
//    written once, read only after flag => readers use PLAIN CACHED loads (4 WGs/XCD share
//    one L2 fill; was per-WG uncached atomics). Writers keep sc0sc1 write-through + vmcnt
//    drain (syncthreads) + relaxed flag: R2's proven ordering.

typedef __attribute__((ext_vector_type(8))) short bf16x8;
typedef __attribute__((ext_vector_type(4))) float f32x4;

__device__ __forceinline__ unsigned short f2bf(float f){
  unsigned u = __float_as_uint(f);
  u += 0x7FFFu + ((u >> 16) & 1u);          // RNE
  return (unsigned short)(u >> 16);
}
__device__ __forceinline__ float b2f(unsigned short h){
  return __uint_as_float(((unsigned)h) << 16);
}
__device__ __forceinline__ ushort4 f4tobf(float4 f){
  ushort4 o; o.x=f2bf(f.x); o.y=f2bf(f.y); o.z=f2bf(f.z); o.w=f2bf(f.w); return o;
}

// ---------------- workspace layout (bytes) ----------------
// flags:    [0x0,      0x1000)   32 flags, 128B stride
// pooled:   [0x30000,  0x50000)  64x512 f32
// w_ih bf16:[0x50000,  0x250000)
// combined: [0x800000, 0x2800000) 32768x512 bf16; REUSED by k_lstm as h-ring: 512 slots x 64KB
// gates:    [0x3000000,0xB000000) 32768x2048 bf16, layout [st][wg][b][u16][g] (aliases q/k/v/ctx)
// q:0x3000000 k:0x4000000 v:0x5000000 ctx:0x6000000 (each 16MB bf16)
// total required ws: 0xB000000 = 184,549,376 B

// K0: w_ih fp32->bf16, and x fp32 -> combined[:, 0:256] bf16
__global__ __launch_bounds__(256) void k_convert(const float* __restrict__ wih,
                                                 const float* __restrict__ x,
                                                 unsigned short* __restrict__ wih_bf,
                                                 unsigned short* __restrict__ comb){
  size_t i = ((size_t)blockIdx.x * 256 + threadIdx.x) * 4;
  if (i < 1048576){
    float4 f = *(const float4*)(wih + i);
    *(ushort4*)(wih_bf + i) = f4tobf(f);
  } else {
    size_t j = i - 1048576;
    if (j < 8388608){
      float4 f = *(const float4*)(x + j);
      size_t m = j >> 8, c = j & 255;
      *(ushort4*)(comb + m*512 + c) = f4tobf(f);
    }
  }
}

// K1: qkv = x @ in_proj_w.T + b ; scale folded into q; writes q/k [n][h][s][d], v transposed [n][h][d][s]
__global__ __launch_bounds__(256) void k_qkv(const unsigned short* __restrict__ xb,
                                             const float* __restrict__ w,
                                             const float* __restrict__ bias,
                                             unsigned short* __restrict__ q,
                                             unsigned short* __restrict__ kk,
                                             unsigned short* __restrict__ v){
  const int nt = blockIdx.x;    // 0..11
  const int mt = blockIdx.y;    // 0..511  (= s, since M-row = s*64+n)
  __shared__ unsigned short Bs[64][264];
  const int t = threadIdx.x;
  { // stage+convert B tile (in_proj_w rows nt*64..+64, k 0..256)
    int row = t >> 2, c0 = (t & 3) * 64;
    const float* src = w + (size_t)(nt*64 + row)*256 + c0;
    #pragma unroll
    for (int i = 0; i < 64; i += 4){
      float4 f = *(const float4*)(src + i);
      *(ushort4*)&Bs[row][c0 + i] = f4tobf(f);
    }
  }
  __syncthreads();
  const int w4 = t >> 6, l = t & 63, lr = l & 15, lc = l >> 4;
  f32x4 acc[4];
  #pragma unroll
  for (int i = 0; i < 4; ++i) acc[i] = (f32x4){0.f,0.f,0.f,0.f};
  const size_t arow = (size_t)(mt*64 + w4*16 + lr) * 512;  // A from combined (bf16 x)
  #pragma unroll
  for (int kt = 0; kt < 8; ++kt){
    bf16x8 a = *(const bf16x8*)(xb + arow + kt*32 + lc*8);
    #pragma unroll
    for (int n4 = 0; n4 < 4; ++n4){
      bf16x8 b = *(const bf16x8*)&Bs[n4*16 + lr][kt*32 + lc*8];
      acc[n4] = __builtin_amdgcn_mfma_f32_16x16x32_bf16(a, b, acc[n4], 0, 0, 0);
    }
  }
  const int s = mt;
  #pragma unroll
  for (int n4 = 0; n4 < 4; ++n4){
    int ncol = nt*64 + n4*16 + lr;
    float bv = bias[ncol];
    int which = ncol >> 8, rem = ncol & 255, hh = rem >> 5, d = rem & 31;
    #pragma unroll
    for (int reg = 0; reg < 4; ++reg){
      int nb = w4*16 + lc*4 + reg;   // batch
      float val = acc[n4][reg] + bv;
      if (which == 0){
        val *= 0.17677669529663687f;  // 1/sqrt(32)
        q[((size_t)(nb*8 + hh)*512 + s)*32 + d] = f2bf(val);
      } else if (which == 1){
        kk[((size_t)(nb*8 + hh)*512 + s)*32 + d] = f2bf(val);
      } else {
        v[((size_t)(nb*8 + hh)*32 + d)*512 + s] = f2bf(val);
      }
    }
  }
}

// K2: attention for one (n,h); Q-tile=32, full-S bf16 score strip in LDS, exp recomputed into PV A-frags
__global__ __launch_bounds__(256) void k_attn(const unsigned short* __restrict__ q,
                                              const unsigned short* __restrict__ k,
                                              const unsigned short* __restrict__ v,
                                              unsigned short* __restrict__ ctx){
  const int nh = blockIdx.x;
  const int n = nh >> 3, h = nh & 7;
  __shared__ unsigned short sc[32][520];
  __shared__ float red[32][8];
  __shared__ float rowmax[32], rowinv[32];
  const unsigned short* qb = q + (size_t)nh * 512 * 32;
  const unsigned short* kb = k + (size_t)nh * 512 * 32;
  const unsigned short* vb = v + (size_t)nh * 32 * 512;
  const int t = threadIdx.x, w4 = t >> 6, l = t & 63, lr = l & 15, lc = l >> 4;
  const int r = t >> 3, cc = t & 7;
  for (int qt = 0; qt < 16; ++qt){
    const int s0 = qt * 32;
    bf16x8 aq0 = *(const bf16x8*)(qb + (size_t)(s0 + lr)*32 + lc*8);
    bf16x8 aq1 = *(const bf16x8*)(qb + (size_t)(s0 + 16 + lr)*32 + lc*8);
    #pragma unroll
    for (int j = 0; j < 8; ++j){
      int ntl = w4*8 + j;
      bf16x8 bk = *(const bf16x8*)(kb + (size_t)(ntl*16 + lr)*32 + lc*8);
      f32x4 d0 = (f32x4){0.f,0.f,0.f,0.f}, d1 = (f32x4){0.f,0.f,0.f,0.f};
      d0 = __builtin_amdgcn_mfma_f32_16x16x32_bf16(aq0, bk, d0, 0, 0, 0);
      d1 = __builtin_amdgcn_mfma_f32_16x16x32_bf16(aq1, bk, d1, 0, 0, 0);
      #pragma unroll
      for (int reg = 0; reg < 4; ++reg){
        sc[lc*4 + reg][ntl*16 + lr]      = f2bf(d0[reg]);
        sc[16 + lc*4 + reg][ntl*16 + lr] = f2bf(d1[reg]);
      }
    }
    __syncthreads();
    float pm = -1e30f;
    for (int i = 0; i < 64; ++i) pm = fmaxf(pm, b2f(sc[r][cc + 8*i]));
    red[r][cc] = pm;
    __syncthreads();
    float mfull = red[r][0];
    #pragma unroll
    for (int i = 1; i < 8; ++i) mfull = fmaxf(mfull, red[r][i]);
    rowmax[r] = mfull;   // benign same-value race across the 8 threads of a row
    __syncthreads();
    float sum = 0.f;
    for (int i = 0; i < 64; ++i) sum += __expf(b2f(sc[r][cc + 8*i]) - mfull);
    red[r][cc] = sum;
    __syncthreads();
    float ss = 0.f;
    #pragma unroll
    for (int i = 0; i < 8; ++i) ss += red[r][i];
    rowinv[r] = 1.f / ss;
    __syncthreads();
    // PV: each wave one 16x16 tile of the 32x32 O
    const int mt = w4 >> 1, ntd = w4 & 1;
    const int arow = mt*16 + lr;
    const float mrow = rowmax[arow];
    f32x4 o = (f32x4){0.f,0.f,0.f,0.f};
    for (int kt = 0; kt < 16; ++kt){
      bf16x8 sv = *(const bf16x8*)&sc[arow][kt*32 + lc*8];
      bf16x8 ap;
      #pragma unroll
      for (int e = 0; e < 8; ++e){
        float p = __expf(b2f((unsigned short)sv[e]) - mrow);
        ap[e] = (short)f2bf(p);
      }
      bf16x8 bv = *(const bf16x8*)(vb + (size_t)(ntd*16 + lr)*512 + kt*32 + lc*8);
      o = __builtin_amdgcn_mfma_f32_16x16x32_bf16(ap, bv, o, 0, 0, 0);
    }
    #pragma unroll
    for (int reg = 0; reg < 4; ++reg){
      int row = mt*16 + lc*4 + reg;
      int d = ntd*16 + lr;
      float val = o[reg] * rowinv[row];
      ctx[((size_t)(s0 + row)*64 + n)*256 + h*32 + d] = f2bf(val);
    }
    __syncthreads();
  }
}

// K3: attn_out = ctx @ mha_out_w.T + b -> combined[:, 256:512]
__global__ __launch_bounds__(256) void k_outproj(const unsigned short* __restrict__ ctx,
                                                 const float* __restrict__ w,
                                                 const float* __restrict__ bias,
                                                 unsigned short* __restrict__ comb){
  const int nt = blockIdx.x;   // 0..3
  const int mt = blockIdx.y;   // 0..511
  __shared__ unsigned short Bs[64][264];
  const int t = threadIdx.x;
  {
    int row = t >> 2, c0 = (t & 3) * 64;
    const float* src = w + (size_t)(nt*64 + row)*256 + c0;
    #pragma unroll
    for (int i = 0; i < 64; i += 4){
      float4 f = *(const float4*)(src + i);
      *(ushort4*)&Bs[row][c0 + i] = f4tobf(f);
    }
  }
  __syncthreads();
  const int w4 = t >> 6, l = t & 63, lr = l & 15, lc = l >> 4;
  f32x4 acc[4];
  #pragma unroll
  for (int i = 0; i < 4; ++i) acc[i] = (f32x4){0.f,0.f,0.f,0.f};
  const size_t arow = (size_t)(mt*64 + w4*16 + lr) * 256;
  #pragma unroll
  for (int kt = 0; kt < 8; ++kt){
    bf16x8 a = *(const bf16x8*)(ctx + arow + kt*32 + lc*8);
    #pragma unroll
    for (int n4 = 0; n4 < 4; ++n4){
      bf16x8 b = *(const bf16x8*)&Bs[n4*16 + lr][kt*32 + lc*8];
      acc[n4] = __builtin_amdgcn_mfma_f32_16x16x32_bf16(a, b, acc[n4], 0, 0, 0);
    }
  }
  #pragma unroll
  for (int n4 = 0; n4 < 4; ++n4){
    int ncol = nt*64 + n4*16 + lr;
    float bv = bias[ncol];
    #pragma unroll
    for (int reg = 0; reg < 4; ++reg){
      int m = mt*64 + w4*16 + lc*4 + reg;
      comb[(size_t)m*512 + 256 + ncol] = f2bf(acc[n4][reg] + bv);
    }
  }
}

// K4: gates_x = combined @ w_ih.T + (b_ih + b_hh), 128x128 tiles, BK=64.
// Output retiled for k_lstm: idx = ((st*32 + wg)*64 + b)*64 + u16*4 + g
//   where m = st*64+b, ncol = g*512 + wg*16 + u16.
__global__ __launch_bounds__(256) void k_gates(const unsigned short* __restrict__ A,
                                               const unsigned short* __restrict__ B,
                                               const float* __restrict__ bih,
                                               const float* __restrict__ bhh,
                                               unsigned short* __restrict__ gates){
  const int ntile = blockIdx.x;  // 0..15
  const int mtile = blockIdx.y;  // 0..255
  __shared__ unsigned short As[128][72], Bss[128][72];
  const int t = threadIdx.x, w4 = t >> 6, l = t & 63, lr = l & 15, lc = l >> 4;
  const int wm = w4 >> 1, wn = w4 & 1;
  f32x4 acc[4][4];
  #pragma unroll
  for (int i = 0; i < 4; ++i)
    #pragma unroll
    for (int j = 0; j < 4; ++j) acc[i][j] = (f32x4){0.f,0.f,0.f,0.f};
  const int srow = t >> 1, half = t & 1;
  const unsigned short* sa = A + (size_t)(mtile*128 + srow)*512 + half*32;
  const unsigned short* sb = B + (size_t)(ntile*128 + srow)*512 + half*32;
  for (int kkk = 0; kkk < 8; ++kkk){
    #pragma unroll
    for (int i = 0; i < 4; ++i){
      *(uint4*)&As [srow][half*32 + i*8] = *(const uint4*)(sa + kkk*64 + i*8);
      *(uint4*)&Bss[srow][half*32 + i*8] = *(const uint4*)(sb + kkk*64 + i*8);
    }
    __syncthreads();
    #pragma unroll
    for (int kt = 0; kt < 2; ++kt){
      bf16x8 af[4], bfr[4];
      #pragma unroll
      for (int i = 0; i < 4; ++i) af[i]  = *(const bf16x8*)&As [wm*64 + i*16 + lr][kt*32 + lc*8];
      #pragma unroll
      for (int i = 0; i < 4; ++i) bfr[i] = *(const bf16x8*)&Bss[wn*64 + i*16 + lr][kt*32 + lc*8];
      #pragma unroll
      for (int i = 0; i < 4; ++i)
        #pragma unroll
        for (int j = 0; j < 4; ++j)
          acc[i][j] = __builtin_amdgcn_mfma_f32_16x16x32_bf16(af[i], bfr[j], acc[i][j], 0, 0, 0);
    }
    __syncthreads();
  }
  #pragma unroll
  for (int i = 0; i < 4; ++i){
    #pragma unroll
    for (int j = 0; j < 4; ++j){
      int ncol = ntile*128 + wn*64 + j*16 + lr;
      int g = ncol >> 9, u = ncol & 511, wg2 = u >> 4, u16 = u & 15;
      float bsum = bih[ncol] + bhh[ncol];
      #pragma unroll
      for (int reg = 0; reg < 4; ++reg){
        int m = mtile*128 + wm*64 + i*16 + lc*4 + reg;
        int st = m >> 6, b = m & 63;
        gates[(((size_t)st*32 + wg2)*64 + b)*64 + u16*4 + g] = f2bf(acc[i][j][reg] + bsum);
      }
    }
  }
}

// K5: persistent LSTM. 32 co-resident WGs, each owns 16 hidden units.
// h travels via a 512-slot write-once ring: writers store sc0sc1 (write-through to coherence
// point), readers use plain cached loads (address never touched before => no stale lines;
// 4 WGs per XCD share one L2 fill). Flags stay relaxed agent-scope atomics.
__global__ __launch_bounds__(256, 1) void k_lstm(const float* __restrict__ whh,
                                                 const unsigned short* __restrict__ gates,
                                                 unsigned short* __restrict__ ring,
                                                 float* __restrict__ pooled,
                                                 int* __restrict__ flags){
  const int wg = blockIdx.x;   // 0..31
  const int j0 = wg * 16;
  __shared__ unsigned short Wl[64][512];   // rows: gate*16+unit ; 64KB
  __shared__ unsigned short hst[64*16];    // 2KB bounce for coalesced h stores
  const int t = threadIdx.x, w4 = t >> 6, l = t & 63, lr = l & 15, lc = l >> 4;
  { // stage w_hh slice fp32->bf16 with chunk swizzle: phys_chunk = logical ^ (row&7)
    const int row = t >> 2;
    const int gate = row >> 4, u = row & 15;
    const float* src = whh + (size_t)(gate*512 + j0 + u) * 512;
    const int cbase = (t & 3) * 16;
    #pragma unroll
    for (int i = 0; i < 16; ++i){
      const int lch = cbase + i;
      float4 f0 = *(const float4*)(src + lch*8);
      float4 f1 = *(const float4*)(src + lch*8 + 4);
      const int pch = lch ^ (row & 7);
      *(ushort4*)&Wl[row][pch*8]     = f4tobf(f0);
      *(ushort4*)&Wl[row][pch*8 + 4] = f4tobf(f1);
    }
  }
  float cst[4]  = {0.f,0.f,0.f,0.f};
  float pool[4] = {0.f,0.f,0.f,0.f};
  const int batch0 = w4*16 + lc*4;
  const int unit = lr;
  unsigned long long gx4[4], nx4[4];
  { // prefetch gates for step 0: 4 x 8B coalesced cached loads
    const unsigned short* g0 = gates + ((size_t)wg << 12);
    #pragma unroll
    for (int reg = 0; reg < 4; ++reg)
      gx4[reg] = *(const unsigned long long*)(g0 + (batch0 + reg)*64 + unit*4);
  }
  __syncthreads();
  for (int st = 0; st < 512; ++st){
    // issue next-step gates prefetch BEFORE the poll so its latency hides behind the wait
    if (st < 511){
      const unsigned short* g0 = gates + (((size_t)(st + 1)*32 + wg) << 12);
      #pragma unroll
      for (int reg = 0; reg < 4; ++reg)
        nx4[reg] = *(const unsigned long long*)(g0 + (batch0 + reg)*64 + unit*4);
    }
    if (st > 0){
      if (t < 32){
        while (__hip_atomic_load(&flags[t*32], __ATOMIC_RELAXED, __HIP_MEMORY_SCOPE_AGENT) < st) { }
      }
      __syncthreads();
    }
    const unsigned short* hr = ring + ((size_t)st << 15);   // 64KB slot
    f32x4 acc[4];
    #pragma unroll
    for (int i = 0; i < 4; ++i) acc[i] = (f32x4){0.f,0.f,0.f,0.f};
    const size_t hrow = (size_t)(w4*16 + lr) * 512;
    #pragma unroll
    for (int kt = 0; kt < 16; ++kt){
      bf16x8 a = *(const bf16x8*)(hr + hrow + kt*32 + lc*8);   // plain cached load
      #pragma unroll
      for (int gg = 0; gg < 4; ++gg){
        bf16x8 b = *(const bf16x8*)&Wl[gg*16 + lr][(((kt*4) + lc) ^ (lr & 7)) * 8];
        acc[gg] = __builtin_amdgcn_mfma_f32_16x16x32_bf16(a, b, acc[gg], 0, 0, 0);
      }
    }
    #pragma unroll
    for (int reg = 0; reg < 4; ++reg){
      union { unsigned long long q; unsigned short u[4]; } ga; ga.q = gx4[reg];
      float gi = acc[0][reg] + b2f(ga.u[0]);
      float gf = acc[1][reg] + b2f(ga.u[1]);
      float gc = acc[2][reg] + b2f(ga.u[2]);
      float go = acc[3][reg] + b2f(ga.u[3]);
      float i_ = 1.f / (1.f + __expf(-gi));
      float f_ = 1.f / (1.f + __expf(-gf));
      float cg = fminf(fmaxf(gc, -20.f), 20.f);
      float e2 = __expf(2.f * cg);
      float g_ = (e2 - 1.f) / (e2 + 1.f);
      float o_ = 1.f / (1.f + __expf(-go));
      float cn = f_ * cst[reg] + i_ * g_;
      cst[reg] = cn;
      float ct = fminf(fmaxf(cn, -20.f), 20.f);
      float e2c = __expf(2.f * ct);
      float th = (e2c - 1.f) / (e2c + 1.f);
      float hh = o_ * th;
      pool[reg] += hh;
      hst[(batch0 + reg)*16 + unit] = f2bf(hh);
    }
    #pragma unroll
    for (int i = 0; i < 4; ++i) gx4[i] = nx4[i];
    __syncthreads();   // hst complete
    if (st < 511){
      { // coalesced write-through h store: 256 threads x 8B = 2KB slice into ring slot st+1
        unsigned short* hw = ring + ((size_t)(st + 1) << 15);
        const int b = t >> 2, o4 = (t & 3) * 4;
        unsigned long long val = *(const unsigned long long*)&hst[b*16 + o4];
        __hip_atomic_store((unsigned long long*)(hw + (size_t)b*512 + j0 + o4), val,
                           __ATOMIC_RELAXED, __HIP_MEMORY_SCOPE_AGENT);
      }
      __syncthreads(); // each wave drains vmcnt before barrier -> all h stores at coherence point
      if (t == 0){
        __hip_atomic_store(&flags[wg*32], st + 1, __ATOMIC_RELAXED, __HIP_MEMORY_SCOPE_AGENT);
      }
    }
  }
  #pragma unroll
  for (int reg = 0; reg < 4; ++reg)
    pooled[(size_t)(batch0 + reg)*512 + j0 + unit] = pool[reg] * (1.f / 512.f);
}

// K6: out = log_sigmoid(pooled @ proj_w.T + proj_b)
__global__ __launch_bounds__(256) void k_final(const float* __restrict__ pooled,
                                               const float* __restrict__ w,
                                               const float* __restrict__ bias,
                                               float* __restrict__ out){
  const int n = blockIdx.x;
  __shared__ float pr[512];
  const int t = threadIdx.x;
  pr[t]       = pooled[(size_t)n*512 + t];
  pr[t + 256] = pooled[(size_t)n*512 + t + 256];
  __syncthreads();
  const float* wr = w + (size_t)t * 512;
  float s = bias[t];
  for (int i = 0; i < 512; i += 4){
    float4 f = *(const float4*)(wr + i);
    s += f.x*pr[i] + f.y*pr[i+1] + f.z*pr[i+2] + f.w*pr[i+3];
  }
  float rres = fminf(s, 0.f) - log1pf(__expf(-fabsf(s)));
  out[(size_t)n*256 + t] = rres;
}

extern "C" void kernel_launch(void* const* d_in, const int* in_sizes, int n_in,
                              void* d_out, int out_size, void* d_ws, size_t ws_size,
                              hipStream_t stream){
  const float* x      = (const float*)d_in[0];
  const float* in_w   = (const float*)d_in[1];
  const float* in_b   = (const float*)d_in[2];
  const float* mo_w   = (const float*)d_in[3];
  const float* mo_b   = (const float*)d_in[4];
  const float* w_ih   = (const float*)d_in[5];
  const float* w_hh   = (const float*)d_in[6];
  const float* b_ih   = (const float*)d_in[7];
  const float* b_hh   = (const float*)d_in[8];
  const float* proj_w = (const float*)d_in[9];
  const float* proj_b = (const float*)d_in[10];
  uint8_t* ws = (uint8_t*)d_ws;
  int*            flags  = (int*)(ws + 0x0);
  float*          pooled = (float*)(ws + 0x30000);
  unsigned short* wihbf  = (unsigned short*)(ws + 0x50000);
  unsigned short* comb   = (unsigned short*)(ws + 0x800000);  // doubles as h-ring in k_lstm
  unsigned short* gates  = (unsigned short*)(ws + 0x3000000);
  unsigned short* qbuf   = (unsigned short*)(ws + 0x3000000); // aliases gates (dead before k_gates)
  unsigned short* kbuf   = (unsigned short*)(ws + 0x4000000);
  unsigned short* vbuf   = (unsigned short*)(ws + 0x5000000);
  unsigned short* ctx    = (unsigned short*)(ws + 0x6000000);

  hipMemsetAsync(ws, 0, 0x1000, stream);  // flags
  hipLaunchKernelGGL(k_convert, dim3(9216),    dim3(256), 0, stream, w_ih, x, wihbf, comb);
  hipLaunchKernelGGL(k_qkv,     dim3(12, 512), dim3(256), 0, stream, comb, in_w, in_b, qbuf, kbuf, vbuf);
  hipLaunchKernelGGL(k_attn,    dim3(512),     dim3(256), 0, stream, qbuf, kbuf, vbuf, ctx);
  hipLaunchKernelGGL(k_outproj, dim3(4, 512),  dim3(256), 0, stream, ctx, mo_w, mo_b, comb);
  hipLaunchKernelGGL(k_gates,   dim3(16, 256), dim3(256), 0, stream, comb, wihbf, b_ih, b_hh, gates);
  hipMemsetAsync(comb, 0, 0x10000, stream);  // h-ring slot 0 = h(-1) = zeros (comb is dead now)
  hipLaunchKernelGGL(k_lstm,    dim3(32),      dim3(256), 0, stream, w_hh, gates, comb, pooled, flags);
  hipLaunchKernelGGL(k_final,   dim3(64),      dim3(256), 0, stream, pooled, proj_w, proj_b, (float*)d_out);
}